// Round 7
// baseline (74.233 us; speedup 1.0000x reference)
//
#include <hip/hip_runtime.h>

#define NCLS 10

typedef _Float16 half8 __attribute__((ext_vector_type(8)));
typedef _Float16 h2 __attribute__((ext_vector_type(2)));
typedef __fp16 fp16x2 __attribute__((ext_vector_type(2)));
typedef float f32x4 __attribute__((ext_vector_type(4)));
typedef unsigned int u32;

#define MFMA(A, B, C) __builtin_amdgcn_mfma_f32_16x16x32_f16(A, B, C, 0, 0, 0)

union U4H8 { uint4 u; half8 h; h2 p[4]; u32 w[4]; };
union U2H4 { uint2 u; h2 p[2]; };
union HCVT { fp16x2 f; h2 h; u32 w; };

// node rows = 8 uint4 chunks (64 f16); physical chunk = c ^ (row&7)
__device__ __forceinline__ int rc(int row, int c) { return (row << 3) | (c ^ (row & 7)); }

__device__ __forceinline__ h2 pk2(float a, float b) {
    HCVT u; u.f = __builtin_amdgcn_cvt_pkrtz(a, b); return u.h;
}
__device__ __forceinline__ u32 packh2(float a, float b) {
    HCVT u; u.f = __builtin_amdgcn_cvt_pkrtz(a, b); return u.w;
}
__device__ __forceinline__ float fdot2f(h2 a, h2 b, float c) {
    return __builtin_amdgcn_fdot2(a, b, c, false);
}
__device__ __forceinline__ float wave_sum(float v) {
#pragma unroll
    for (int m = 1; m < 64; m <<= 1) v += __shfl_xor(v, m, 64);
    return v;
}
__device__ __forceinline__ float red4(float v) {
    v += __shfl_xor(v, 16, 64);
    v += __shfl_xor(v, 32, 64);
    return v;
}

// wf[k][kb][mb]: lane (pl,g) elem e = W_k[32kb+8g+e][16mb+pl]  (A-frag of W^T)
__device__ __forceinline__ void build_wf(const float* wfp, half8 (&wf)[2][2][4],
                                         int pl, int g) {
#pragma unroll
    for (int k = 0; k < 2; ++k)
#pragma unroll
        for (int kb = 0; kb < 2; ++kb)
#pragma unroll
            for (int mb = 0; mb < 4; ++mb) {
                U4H8 fr;
#pragma unroll
                for (int e2 = 0; e2 < 4; ++e2) {
                    int i0 = 32 * kb + 8 * g + 2 * e2;
                    int j = 16 * mb + pl;
                    fr.w[e2] = packh2(wfp[k * 4096 + i0 * 64 + j],
                                      wfp[k * 4096 + (i0 + 1) * 64 + j]);
                }
                wf[k][kb][mb] = fr.h;
            }
}

// N-stream 16-pair combine (compute only; caller writes). EXACT: true norms.
template <int N, bool EXACT>
__device__ __forceinline__ void combine(const uint4* src, const int (&rowL)[N],
                                        const int (&rowR)[N],
                                        const half8 (&wf)[2][2][4], int pl, int g,
                                        U4H8 (&q)[N][2]) {
    U4H8 La[N][2], Ra[N][2];
#pragma unroll
    for (int n = 0; n < N; ++n)
#pragma unroll
        for (int kb = 0; kb < 2; ++kb) {
            La[n][kb].u = src[rc(rowL[n], g + 4 * kb)];
            Ra[n][kb].u = src[rc(rowR[n], g + 4 * kb)];
        }
    const uint2* s2 = (const uint2*)src;
    U2H4 rv[N][4];
#pragma unroll
    for (int n = 0; n < N; ++n)
#pragma unroll
        for (int mb = 0; mb < 4; ++mb)
            rv[n][mb].u = s2[rc(rowR[n], 2 * mb + (g >> 1)) * 2 + (g & 1)];
    float s0[N], s1[N], lr[N], ll[N], rr[N];
#pragma unroll
    for (int n = 0; n < N; ++n) { s0[n] = 0.f; s1[n] = 0.f; lr[n] = 0.f; ll[n] = 0.f; rr[n] = 0.f; }
#pragma unroll
    for (int mb = 0; mb < 4; ++mb)
#pragma unroll
        for (int n = 0; n < N; ++n) {
            f32x4 t0 = {0.f, 0.f, 0.f, 0.f}, t1 = {0.f, 0.f, 0.f, 0.f};
#pragma unroll
            for (int kb = 0; kb < 2; ++kb) {
                t0 = MFMA(wf[0][kb][mb], La[n][kb].h, t0);
                t1 = MFMA(wf[1][kb][mb], La[n][kb].h, t1);
            }
            s0[n] = fdot2f(pk2(t0[0], t0[1]), rv[n][mb].p[0],
                           fdot2f(pk2(t0[2], t0[3]), rv[n][mb].p[1], s0[n]));
            s1[n] = fdot2f(pk2(t1[0], t1[1]), rv[n][mb].p[0],
                           fdot2f(pk2(t1[2], t1[3]), rv[n][mb].p[1], s1[n]));
        }
#pragma unroll
    for (int n = 0; n < N; ++n)
#pragma unroll
        for (int kb = 0; kb < 2; ++kb)
#pragma unroll
            for (int i = 0; i < 4; ++i) {
                h2 l2 = La[n][kb].p[i], r2 = Ra[n][kb].p[i];
                lr[n] = fdot2f(l2, r2, lr[n]);
                if (EXACT) {
                    ll[n] = fdot2f(l2, l2, ll[n]);
                    rr[n] = fdot2f(r2, r2, rr[n]);
                }
            }
#pragma unroll
    for (int n = 0; n < N; ++n) {
        s0[n] = red4(s0[n]); s1[n] = red4(s1[n]); lr[n] = red4(lr[n]);
        if (EXACT) { ll[n] = red4(ll[n]); rr[n] = red4(rr[n]); }
    }
#pragma unroll
    for (int n = 0; n < N; ++n) {
        float u = __expf(s1[n] - s0[n]);
        float a0 = __builtin_amdgcn_rcpf(1.f + u);
        float a1 = 1.f - a0;
        float ms;
        if (EXACT)
            ms = (a0 * a0 * ll[n] + 2.f * a0 * a1 * lr[n] + a1 * a1 * rr[n]) * (1.f / 64.f);
        else
            ms = a0 * a0 + a1 * a1 + a0 * a1 * lr[n] * (2.f / 64.f);
        float sc = __builtin_amdgcn_rcpf(__builtin_amdgcn_sqrtf(ms + 1e-6f) + 1e-6f);
        h2 c0 = pk2(a0 * sc, a0 * sc), c1 = pk2(a1 * sc, a1 * sc);
#pragma unroll
        for (int kb = 0; kb < 2; ++kb)
#pragma unroll
            for (int i = 0; i < 4; ++i)
                q[n][kb].p[i] = c0 * La[n][kb].p[i] + c1 * Ra[n][kb].p[i];
    }
}

// register->global capture: write q (row `node` at level `lev`) into matching sv slots
__device__ __forceinline__ void capg(uint4* ws4, int b, int lev, int node, int lo,
                                     int hi, const U4H8 (&q)[2], int g) {
    int il = lo >> lev, ih = hi >> lev;
    int cnt = 1024 >> lev;
    int base = (b * 52 + lev * 4) * 8;
    if (node == il) { ws4[base + g] = q[0].u; ws4[base + 4 + g] = q[1].u; }
    if (((il ^ 1) < cnt) && node == (il ^ 1)) { ws4[base + 8 + g] = q[0].u; ws4[base + 12 + g] = q[1].u; }
    if (node == ih) { ws4[base + 16 + g] = q[0].u; ws4[base + 20 + g] = q[1].u; }
    if (((ih ^ 1) < cnt) && node == (ih ^ 1)) { ws4[base + 24 + g] = q[0].u; ws4[base + 28 + g] = q[1].u; }
}

// ======================= kernel 1: fold =======================
__global__ void __launch_bounds__(512, 2) fold_kernel(
    const int* __restrict__ x, const int* __restrict__ qlo_p,
    const int* __restrict__ qhi_p, const float* __restrict__ emb,
    const float* __restrict__ rule_w, uint4* __restrict__ ws4) {
    __shared__ uint4 tr4[8 * 64 * 8];  // 64 KB: W staging, then 8 private 64-row regions
    __shared__ uint4 ermsh[11 * 8];

    const int tid = threadIdx.x;
    const int lane = tid & 63;
    const int wid = tid >> 6;
    const int pl = lane & 15;
    const int g = lane >> 4;
    const int b = blockIdx.x;
    const int lo = qlo_p[b];
    const int hi = qhi_p[b];

    const uint4* rw4 = (const uint4*)rule_w;
#pragma unroll
    for (int i = 0; i < 4; ++i) tr4[i * 512 + tid] = rw4[i * 512 + tid];
    __syncthreads();

    half8 wf[2][2][4];
    build_wf((const float*)tr4, wf, pl, g);
    for (int row = wid; row < 11; row += 8) {
        float e = emb[row * 64 + lane];
        float ms = wave_sum(e * e) * (1.f / 64.f);
        float v = e * __builtin_amdgcn_rcpf(__builtin_amdgcn_sqrtf(ms + 1e-6f) + 1e-6f);
        ((_Float16*)ermsh)[rc(row, lane >> 3) * 8 + (lane & 7)] = (_Float16)v;
    }
    __syncthreads();  // wf + ermsh ready before fold overwrites tr4

    // level-0 captures (leaves lo, lo^1, hi, hi^1) direct to global
    if (wid == 0 && lane < 16) {
        int slot = lane >> 2, gg = lane & 3;
        int t = (slot == 0) ? lo : (slot == 1) ? (lo ^ 1) : (slot == 2) ? hi : (hi ^ 1);
        int cls = x[b * 1024 + t];
        int base = (b * 52 + slot) * 8;
        ws4[base + gg] = ermsh[rc(cls, gg)];
        ws4[base + 4 + gg] = ermsh[rc(cls, gg + 4)];
    }

    uint4* wtr = &tr4[wid * 512];  // 64 private rows
    const int2* x2 = (const int2*)x;
    U4H8 q[2][2];

    // lev1: 64 pairs = 4 chunks = 2 calls of <2>; leaves straight from ermsh
#pragma unroll 1
    for (int h = 0; h < 2; ++h) {
        int P0 = (2 * h) * 16 + pl, P1 = (2 * h + 1) * 16 + pl;
        int2 ca = x2[b * 512 + wid * 64 + P0];
        int2 cb = x2[b * 512 + wid * 64 + P1];
        int rL[2] = {ca.x, cb.x}, rR[2] = {ca.y, cb.y};
        combine<2, false>(ermsh, rL, rR, wf, pl, g, q);
        wtr[rc(P0, g)] = q[0][0].u; wtr[rc(P0, g + 4)] = q[0][1].u;
        wtr[rc(P1, g)] = q[1][0].u; wtr[rc(P1, g + 4)] = q[1][1].u;
        capg(ws4, b, 1, wid * 64 + P0, lo, hi, q[0], g);
        capg(ws4, b, 1, wid * 64 + P1, lo, hi, q[1], g);
    }
    // lev2: 32 pairs = 1 call of <2>
    {
        int rL[2] = {2 * pl, 32 + 2 * pl}, rR[2] = {2 * pl + 1, 33 + 2 * pl};
        combine<2, false>(wtr, rL, rR, wf, pl, g, q);
        wtr[rc(pl, g)] = q[0][0].u; wtr[rc(pl, g + 4)] = q[0][1].u;
        wtr[rc(16 + pl, g)] = q[1][0].u; wtr[rc(16 + pl, g + 4)] = q[1][1].u;
        capg(ws4, b, 2, wid * 32 + pl, lo, hi, q[0], g);
        capg(ws4, b, 2, wid * 32 + 16 + pl, lo, hi, q[1], g);
    }
    // lev3..7: single partial chunks
#pragma unroll 1
    for (int lev = 3; lev <= 7; ++lev) {
        int np = 128 >> lev;  // pairs this level (16,8,4,2,1)
        int Pr = pl < np ? pl : np - 1;
        int rL[1] = {2 * Pr}, rR[1] = {2 * Pr + 1};
        U4H8 q1[1][2];
        combine<1, false>(wtr, rL, rR, wf, pl, g, q1);
        if (pl < np) {
            wtr[rc(Pr, g)] = q1[0][0].u;
            wtr[rc(Pr, g + 4)] = q1[0][1].u;
            capg(ws4, b, lev, wid * np + pl, lo, hi, q1[0], g);
            if (lev == 7) {  // root of this subtree -> ws row 44+wid
                int base = (b * 52 + 44 + wid) * 8;
                ws4[base + g] = q1[0][0].u;
                ws4[base + 4 + g] = q1[0][1].u;
            }
        }
    }
}

// ======================= kernel 2: tail walks =======================
// per-wave scratch rows: 0-43 sv, 44-51 roots, 52 inf(raw), 53 res_lo, 54 res_hi,
// 55-58 lev8 out, 59-60 lev9 out, 61 lev10 out
__global__ void __launch_bounds__(256, 1) tail_kernel(
    const int* __restrict__ qlo_p, const int* __restrict__ qhi_p,
    const float* __restrict__ emb, const float* __restrict__ rule_w,
    const float* __restrict__ lin_w, float* __restrict__ out,
    const uint4* __restrict__ ws4) {
    __shared__ uint4 Wst[2048];           // 32 KB
    __shared__ uint4 scr_all[4 * 62 * 8]; // 31.75 KB

    const int tid = threadIdx.x;
    const int lane = tid & 63;
    const int wid = tid >> 6;
    const int pl = lane & 15;
    const int g = lane >> 4;
    const int b = blockIdx.x * 4 + wid;

    const uint4* rw4 = (const uint4*)rule_w;
    for (int i = tid; i < 2048; i += 256) Wst[i] = rw4[i];
    __syncthreads();
    half8 wf[2][2][4];
    build_wf((const float*)Wst, wf, pl, g);

    uint4* scr = &scr_all[wid * 62 * 8];
    for (int idx = lane; idx < 52 * 8; idx += 64) {
        int row = idx >> 3, c = idx & 7;
        scr[rc(row, c)] = ws4[(b * 52) * 8 + idx];
    }
    if (lane < 32) {  // raw inf token (embedding row 10) as f16 -> row 52
        u32 w = packh2(emb[640 + 2 * lane], emb[640 + 2 * lane + 1]);
        ((u32*)scr)[rc(52, lane >> 2) * 4 + (lane & 3)] = w;
    }
    const int lo = qlo_p[b];
    const int hi = qhi_p[b];
    asm volatile("s_waitcnt lgkmcnt(0) vmcnt(0)" ::: "memory");

    int cur_lo = 0, cur_hi = 2;  // lev0: res rows = sv slot0 / slot2
#pragma unroll 1
    for (int lev = 1; lev <= 10; ++lev) {
        int il = lo >> lev, ih = hi >> lev;
        int ilc = lo >> (lev - 1), ihc = hi >> (lev - 1);
        auto rowidx = [&](int c) -> int {
            if (c == ilc) return cur_lo;
            if (c == ihc) return cur_hi;
            int clow = c << (lev - 1);
            int chigh = clow + (1 << (lev - 1)) - 1;
            bool inside = (lo <= clow) && (hi >= chigh);
            if (!inside) return 52;
            return (lev - 1) * 4 + ((c == (ilc ^ 1)) ? 1 : 3);
        };
        int rowL = 0, rowR = 0;
        if (pl == 8) { rowL = rowidx(2 * il); rowR = rowidx(2 * il + 1); }
        else if (pl == 9) { rowL = rowidx(2 * ih); rowR = rowidx(2 * ih + 1); }
        else if (lev == 1 && pl < 4) { rowL = 44 + 2 * pl; rowR = 45 + 2 * pl; }
        else if (lev == 2 && pl < 2) { rowL = 55 + 2 * pl; rowR = 56 + 2 * pl; }
        else if (lev == 3 && pl == 0) { rowL = 59; rowR = 60; }
        int rLa[1] = {rowL}, rRa[1] = {rowR};
        U4H8 q[1][2];
        combine<1, true>(scr, rLa, rRa, wf, pl, g, q);
        // merged top levels: outputs + sv captures (lev8..10)
        if (lev <= 3) {
            int L2 = lev + 7;
            int cnt = 1 << (10 - L2);
            int il2 = lo >> L2, ih2 = hi >> L2;
            bool a2 = (lev == 1) ? (pl < 4) : ((lev == 2) ? (pl < 2) : (pl == 0));
            if (a2) {
                int topdst = (lev == 1) ? (55 + pl) : ((lev == 2) ? (59 + pl) : 61);
                scr[rc(topdst, g)] = q[0][0].u;
                scr[rc(topdst, g + 4)] = q[0][1].u;
                int svb = L2 * 4;
                if (pl == il2) { scr[rc(svb, g)] = q[0][0].u; scr[rc(svb, g + 4)] = q[0][1].u; }
                if (((il2 ^ 1) < cnt) && pl == (il2 ^ 1)) { scr[rc(svb + 1, g)] = q[0][0].u; scr[rc(svb + 1, g + 4)] = q[0][1].u; }
                if (pl == ih2) { scr[rc(svb + 2, g)] = q[0][0].u; scr[rc(svb + 2, g + 4)] = q[0][1].u; }
                if (((ih2 ^ 1) < cnt) && pl == (ih2 ^ 1)) { scr[rc(svb + 3, g)] = q[0][0].u; scr[rc(svb + 3, g + 4)] = q[0][1].u; }
            }
        }
        // res updates
        {
            int low = il << lev, high = low + (1 << lev) - 1;
            bool ins = (lo <= low) && (hi >= high);
            if (ins) cur_lo = lev * 4;
            else {
                if (pl == 8) { scr[rc(53, g)] = q[0][0].u; scr[rc(53, g + 4)] = q[0][1].u; }
                cur_lo = 53;
            }
            int low2 = ih << lev, high2 = low2 + (1 << lev) - 1;
            bool ins2 = (lo <= low2) && (hi >= high2);
            if (ins2) cur_hi = lev * 4 + 2;
            else {
                if (pl == 9) { scr[rc(54, g)] = q[0][0].u; scr[rc(54, g + 4)] = q[0][1].u; }
                cur_hi = 54;
            }
        }
        asm volatile("s_waitcnt lgkmcnt(0)" ::: "memory");
    }
    // final linear
    float rv = (float)((_Float16*)scr)[rc(cur_lo, lane >> 3) * 8 + (lane & 7)];
#pragma unroll
    for (int c = 0; c < NCLS; ++c) {
        float s = wave_sum(rv * lin_w[c * 64 + lane]);
        if (lane == 0) out[b * NCLS + c] = s;
    }
}

extern "C" void kernel_launch(void* const* d_in, const int* in_sizes, int n_in,
                              void* d_out, int out_size, void* d_ws, size_t ws_size,
                              hipStream_t stream) {
    const int* x = (const int*)d_in[0];
    const int* qlo = (const int*)d_in[1];
    const int* qhi = (const int*)d_in[2];
    const float* emb = (const float*)d_in[3];
    const float* rule_w = (const float*)d_in[4];
    const float* lin_w = (const float*)d_in[5];
    float* out = (float*)d_out;
    uint4* ws4 = (uint4*)d_ws;  // needs 1024*52*128 B = 6.8 MB
    fold_kernel<<<1024, 512, 0, stream>>>(x, qlo, qhi, emb, rule_w, ws4);
    tail_kernel<<<256, 256, 0, stream>>>(qlo, qhi, emb, rule_w, lin_w, out, ws4);
}

// Round 8
// 57.678 us; speedup vs baseline: 1.2870x; 1.2870x over previous
//
#include <hip/hip_runtime.h>

#define NCLS 10

typedef _Float16 half8 __attribute__((ext_vector_type(8)));
typedef _Float16 h2 __attribute__((ext_vector_type(2)));
typedef __fp16 fp16x2 __attribute__((ext_vector_type(2)));
typedef float f32x4 __attribute__((ext_vector_type(4)));
typedef unsigned int u32;

#define MFMA(A, B, C) __builtin_amdgcn_mfma_f32_16x16x32_f16(A, B, C, 0, 0, 0)

union U4H8 { uint4 u; half8 h; h2 p[4]; u32 w[4]; };
union U2H4 { uint2 u; h2 p[2]; };
union HCVT { fp16x2 f; h2 h; u32 w; };

// node rows = 8 uint4 chunks (64 f16); physical chunk = c ^ (row&7)
__device__ __forceinline__ int rc(int row, int c) { return (row << 3) | (c ^ (row & 7)); }
__device__ __forceinline__ h2 pk2(float a, float b) { HCVT u; u.f = __builtin_amdgcn_cvt_pkrtz(a, b); return u.h; }
__device__ __forceinline__ u32 packh2(float a, float b) { HCVT u; u.f = __builtin_amdgcn_cvt_pkrtz(a, b); return u.w; }
__device__ __forceinline__ float fdot2f(h2 a, h2 b, float c) { return __builtin_amdgcn_fdot2(a, b, c, false); }
__device__ __forceinline__ float wave_sum(float v) {
#pragma unroll
    for (int m = 1; m < 64; m <<= 1) v += __shfl_xor(v, m, 64);
    return v;
}
__device__ __forceinline__ float red4(float v) {
    v += __shfl_xor(v, 16, 64);
    v += __shfl_xor(v, 32, 64);
    return v;
}

// N-stream 16-pair combine. Single matvec with Wd = W1-W0 (softmax needs only the
// score DIFFERENCE). EXACT: true norms (inf token may appear); else unit-RMS inputs.
template <int N, bool EXACT>
__device__ __forceinline__ void combine(const uint4* src, const int (&rowL)[N],
                                        const int (&rowR)[N], const half8 (&wfd)[2][4],
                                        int pl, int g, U4H8 (&q)[N][2]) {
    U4H8 La[N][2], Ra[N][2];
#pragma unroll
    for (int n = 0; n < N; ++n)
#pragma unroll
        for (int kb = 0; kb < 2; ++kb) {
            La[n][kb].u = src[rc(rowL[n], g + 4 * kb)];
            Ra[n][kb].u = src[rc(rowR[n], g + 4 * kb)];
        }
    const uint2* s2 = (const uint2*)src;
    U2H4 rv[N][4];
#pragma unroll
    for (int n = 0; n < N; ++n)
#pragma unroll
        for (int mb = 0; mb < 4; ++mb)
            rv[n][mb].u = s2[rc(rowR[n], 2 * mb + (g >> 1)) * 2 + (g & 1)];
    float sd[N], lr[N], ll[N], rr[N];
#pragma unroll
    for (int n = 0; n < N; ++n) { sd[n] = 0.f; lr[n] = 0.f; ll[n] = 0.f; rr[n] = 0.f; }
#pragma unroll
    for (int mb = 0; mb < 4; ++mb)
#pragma unroll
        for (int n = 0; n < N; ++n) {
            f32x4 t = {0.f, 0.f, 0.f, 0.f};
#pragma unroll
            for (int kb = 0; kb < 2; ++kb) t = MFMA(wfd[kb][mb], La[n][kb].h, t);
            sd[n] = fdot2f(pk2(t[0], t[1]), rv[n][mb].p[0],
                           fdot2f(pk2(t[2], t[3]), rv[n][mb].p[1], sd[n]));
        }
#pragma unroll
    for (int n = 0; n < N; ++n)
#pragma unroll
        for (int kb = 0; kb < 2; ++kb)
#pragma unroll
            for (int i = 0; i < 4; ++i) {
                h2 l2 = La[n][kb].p[i], r2 = Ra[n][kb].p[i];
                lr[n] = fdot2f(l2, r2, lr[n]);
                if (EXACT) { ll[n] = fdot2f(l2, l2, ll[n]); rr[n] = fdot2f(r2, r2, rr[n]); }
            }
#pragma unroll
    for (int n = 0; n < N; ++n) {
        sd[n] = red4(sd[n]); lr[n] = red4(lr[n]);
        if (EXACT) { ll[n] = red4(ll[n]); rr[n] = red4(rr[n]); }
    }
#pragma unroll
    for (int n = 0; n < N; ++n) {
        float u = __expf(sd[n]);  // exp(s1-s0)
        float a0 = __builtin_amdgcn_rcpf(1.f + u), a1 = 1.f - a0;
        float ms = EXACT ? (a0 * a0 * ll[n] + 2.f * a0 * a1 * lr[n] + a1 * a1 * rr[n]) * (1.f / 64.f)
                         : a0 * a0 + a1 * a1 + a0 * a1 * lr[n] * (2.f / 64.f);
        float sc = __builtin_amdgcn_rcpf(__builtin_amdgcn_sqrtf(ms + 1e-6f) + 1e-6f);
        h2 c0 = pk2(a0 * sc, a0 * sc), c1 = pk2(a1 * sc, a1 * sc);
#pragma unroll
        for (int kb = 0; kb < 2; ++kb)
#pragma unroll
            for (int i = 0; i < 4; ++i)
                q[n][kb].p[i] = c0 * La[n][kb].p[i] + c1 * Ra[n][kb].p[i];
    }
}

// ws layout (uint4 units): [0..511] Wd frags; [512..607] ermsh rows 0-11 (11 RMS'd +
// raw inf) linear; batch b rows at 1024 + (b*140 + r)*8: r 0-127 lev3 nodes,
// 128-139 sv lev0-2 (4 slots each). Total ~18 MB of d_ws.

__device__ __forceinline__ void load_wfd(const uint4* ws4, half8 (&wfd)[2][4], int lane) {
#pragma unroll
    for (int fm = 0; fm < 8; ++fm) {
        U4H8 t;
        t.u = ws4[fm * 64 + lane];
        wfd[fm >> 2][fm & 3] = t.h;
    }
}

// ======================= kernel 0: setup =======================
__global__ void setup_kernel(const float* __restrict__ emb,
                             const float* __restrict__ rule_w, uint4* __restrict__ ws4) {
    int tid = threadIdx.x;
    int idx = blockIdx.x * 256 + tid;  // 0..2047
    {
        int e2 = idx & 3, lane = (idx >> 2) & 63, fm = idx >> 8;
        int kb = fm >> 2, mb = fm & 3, pl = lane & 15, g = lane >> 4;
        int i0 = 32 * kb + 8 * g + 2 * e2, j = 16 * mb + pl;
        float d0 = rule_w[4096 + i0 * 64 + j] - rule_w[i0 * 64 + j];
        float d1 = rule_w[4096 + (i0 + 1) * 64 + j] - rule_w[(i0 + 1) * 64 + j];
        ((u32*)ws4)[idx] = packh2(d0, d1);
    }
    if (blockIdx.x == 0 && tid < 64) {
        int lane = tid;
        u32* eg = (u32*)(ws4 + 512);
        for (int r = 0; r < 11; ++r) {
            float e = emb[r * 64 + lane];
            float ms = wave_sum(e * e) * (1.f / 64.f);
            float v = e * __builtin_amdgcn_rcpf(__builtin_amdgcn_sqrtf(ms + 1e-6f) + 1e-6f);
            u32 w = packh2(v, __shfl_xor(v, 1, 64));
            if ((lane & 1) == 0) eg[r * 32 + (lane >> 1)] = w;
        }
        float e = emb[640 + lane];  // raw inf token -> row 11
        u32 w = packh2(e, __shfl_xor(e, 1, 64));
        if ((lane & 1) == 0) eg[11 * 32 + (lane >> 1)] = w;
    }
}

// capture lev1/lev2 node (in regs) to global sv slots
__device__ __forceinline__ void capg(uint4* ws4, long bb, int lev, int node, int lo,
                                     int hi, const U4H8 (&qq)[2], int g) {
    int il = lo >> lev, ih = hi >> lev;
    long base = bb + (long)(128 + lev * 4) * 8;
    if (node == il)       { ws4[base + g] = qq[0].u;      ws4[base + 4 + g] = qq[1].u; }
    if (node == (il ^ 1)) { ws4[base + 8 + g] = qq[0].u;  ws4[base + 12 + g] = qq[1].u; }
    if (node == ih)       { ws4[base + 16 + g] = qq[0].u; ws4[base + 20 + g] = qq[1].u; }
    if (node == (ih ^ 1)) { ws4[base + 24 + g] = qq[0].u; ws4[base + 28 + g] = qq[1].u; }
}

// ======================= kernel 1: fold lev1-3 (wave = one 128-leaf subtree) ========
__global__ void __launch_bounds__(256, 3) fold_kernel(
    const int* __restrict__ x, const int* __restrict__ qlo_p,
    const int* __restrict__ qhi_p, uint4* __restrict__ ws4) {
    __shared__ uint4 trs[4 * 64 * 8 + 12 * 8];  // 4 wave regions + ermsh
    uint4* ermsh = &trs[2048];
    const int tid = threadIdx.x, lane = tid & 63, wid = tid >> 6;
    const int pl = lane & 15, g = lane >> 4;
    const int b = blockIdx.x >> 1, half = blockIdx.x & 1, s = half * 4 + wid;
    const int lo = qlo_p[b], hi = qhi_p[b];

    half8 wfd[2][4];
    load_wfd(ws4, wfd, lane);
    if (tid < 96) { int r = tid >> 3, c = tid & 7; ermsh[rc(r, c)] = ws4[512 + tid]; }
    __syncthreads();

    long bb = 1024 + (long)b * 140 * 8;
    if (half == 0 && wid == 0 && lane < 32) {  // lev0 sv (RMS'd leaves)
        int slot = lane >> 3, c = lane & 7;
        int t = (slot == 0) ? lo : (slot == 1) ? (lo ^ 1) : (slot == 2) ? hi : (hi ^ 1);
        int cls = x[b * 1024 + t];
        ws4[bb + (long)(128 + slot) * 8 + c] = ermsh[rc(cls, c)];
    }

    uint4* wtr = &trs[wid * 512];  // 64 private rows
    const int2* x2 = (const int2*)x;
    int2 c00 = x2[b * 512 + s * 64 + pl];
    int2 c01 = x2[b * 512 + s * 64 + 16 + pl];
    int2 c10 = x2[b * 512 + s * 64 + 32 + pl];
    int2 c11 = x2[b * 512 + s * 64 + 48 + pl];
    U4H8 q[2][2];
    // lev1 pairs 0-31
    {
        int rL[2] = {c00.x, c01.x}, rR[2] = {c00.y, c01.y};
        combine<2, false>(ermsh, rL, rR, wfd, pl, g, q);
        wtr[rc(pl, g)] = q[0][0].u;      wtr[rc(pl, g + 4)] = q[0][1].u;
        wtr[rc(16 + pl, g)] = q[1][0].u; wtr[rc(16 + pl, g + 4)] = q[1][1].u;
        capg(ws4, bb, 1, s * 64 + pl, lo, hi, q[0], g);
        capg(ws4, bb, 1, s * 64 + 16 + pl, lo, hi, q[1], g);
    }
    // lev1 pairs 32-63
    {
        int rL[2] = {c10.x, c11.x}, rR[2] = {c10.y, c11.y};
        combine<2, false>(ermsh, rL, rR, wfd, pl, g, q);
        wtr[rc(32 + pl, g)] = q[0][0].u; wtr[rc(32 + pl, g + 4)] = q[0][1].u;
        wtr[rc(48 + pl, g)] = q[1][0].u; wtr[rc(48 + pl, g + 4)] = q[1][1].u;
        capg(ws4, bb, 1, s * 64 + 32 + pl, lo, hi, q[0], g);
        capg(ws4, bb, 1, s * 64 + 48 + pl, lo, hi, q[1], g);
    }
    // lev2 (32 pairs)
    {
        int rL[2] = {2 * pl, 32 + 2 * pl}, rR[2] = {2 * pl + 1, 33 + 2 * pl};
        combine<2, false>(wtr, rL, rR, wfd, pl, g, q);
        wtr[rc(pl, g)] = q[0][0].u;      wtr[rc(pl, g + 4)] = q[0][1].u;
        wtr[rc(16 + pl, g)] = q[1][0].u; wtr[rc(16 + pl, g + 4)] = q[1][1].u;
        capg(ws4, bb, 2, s * 32 + pl, lo, hi, q[0], g);
        capg(ws4, bb, 2, s * 32 + 16 + pl, lo, hi, q[1], g);
    }
    // lev3 (16 pairs) -> straight to global lev3 rows
    {
        int rL[1] = {2 * pl}, rR[1] = {2 * pl + 1};
        U4H8 q1[1][2];
        combine<1, false>(wtr, rL, rR, wfd, pl, g, q1);
        long gr = bb + (long)(s * 16 + pl) * 8;
        ws4[gr + g] = q1[0][0].u;
        ws4[gr + 4 + g] = q1[0][1].u;
    }
}

// ======================= kernel 2: top fold (lev4-10) + query walk ==================
// per-wave scratch rows: 0-127 tree (in-place down-fold), 128+l*4+s sv (l=0..10),
// 172 inf(raw), 173 res_lo, 174 res_hi, 175 pad
__global__ void __launch_bounds__(128, 2) topwalk_kernel(
    const int* __restrict__ qlo_p, const int* __restrict__ qhi_p,
    const float* __restrict__ lin_w, float* __restrict__ out,
    uint4* __restrict__ ws4) {
    __shared__ uint4 scr_all[2 * 176 * 8];  // 44 KB
    const int tid = threadIdx.x, lane = tid & 63, wid = tid >> 6;
    const int pl = lane & 15, g = lane >> 4;
    const int b = blockIdx.x * 2 + wid;
    const int lo = qlo_p[b], hi = qhi_p[b];

    half8 wfd[2][4];
    load_wfd(ws4, wfd, lane);
    uint4* scr = &scr_all[wid * 176 * 8];
    long bb = 1024 + (long)b * 140 * 8;
    for (int idx = lane; idx < 140 * 8; idx += 64) {
        int r = idx >> 3, c = idx & 7;
        scr[rc(r, c)] = ws4[bb + idx];
    }
    if (lane < 8) scr[rc(172, lane)] = ws4[512 + 88 + lane];  // raw inf row
    // sv lev3 capture (before lev4 overwrites rows 0-63)
    if (lane < 32) {
        int slot = lane >> 3, c = lane & 7;
        int il3 = lo >> 3, ih3 = hi >> 3;
        int t = (slot == 0) ? il3 : (slot == 1) ? (il3 ^ 1) : (slot == 2) ? ih3 : (ih3 ^ 1);
        scr[rc(140 + slot, c)] = scr[rc(t, c)];
    }

    auto capl = [&](int lev, int node, const U4H8 (&qq)[2]) {
        int il = lo >> lev, ih = hi >> lev, cnt = 1024 >> lev;
        int svb = 128 + lev * 4;
        if (node == il) { scr[rc(svb, g)] = qq[0].u; scr[rc(svb, g + 4)] = qq[1].u; }
        if (((il ^ 1) < cnt) && node == (il ^ 1)) { scr[rc(svb + 1, g)] = qq[0].u; scr[rc(svb + 1, g + 4)] = qq[1].u; }
        if (node == ih) { scr[rc(svb + 2, g)] = qq[0].u; scr[rc(svb + 2, g + 4)] = qq[1].u; }
        if (((ih ^ 1) < cnt) && node == (ih ^ 1)) { scr[rc(svb + 3, g)] = qq[0].u; scr[rc(svb + 3, g + 4)] = qq[1].u; }
    };

    U4H8 q[2][2];
    // lev4 (64 pairs): 2 calls <2>
    {
        int rL[2] = {2 * pl, 32 + 2 * pl}, rR[2] = {2 * pl + 1, 33 + 2 * pl};
        combine<2, false>(scr, rL, rR, wfd, pl, g, q);
        scr[rc(pl, g)] = q[0][0].u;      scr[rc(pl, g + 4)] = q[0][1].u;
        scr[rc(16 + pl, g)] = q[1][0].u; scr[rc(16 + pl, g + 4)] = q[1][1].u;
        capl(4, pl, q[0]); capl(4, 16 + pl, q[1]);
    }
    {
        int rL[2] = {64 + 2 * pl, 96 + 2 * pl}, rR[2] = {65 + 2 * pl, 97 + 2 * pl};
        combine<2, false>(scr, rL, rR, wfd, pl, g, q);
        scr[rc(32 + pl, g)] = q[0][0].u; scr[rc(32 + pl, g + 4)] = q[0][1].u;
        scr[rc(48 + pl, g)] = q[1][0].u; scr[rc(48 + pl, g + 4)] = q[1][1].u;
        capl(4, 32 + pl, q[0]); capl(4, 48 + pl, q[1]);
    }
    // lev5 (32 pairs): 1 call <2>
    {
        int rL[2] = {2 * pl, 32 + 2 * pl}, rR[2] = {2 * pl + 1, 33 + 2 * pl};
        combine<2, false>(scr, rL, rR, wfd, pl, g, q);
        scr[rc(pl, g)] = q[0][0].u;      scr[rc(pl, g + 4)] = q[0][1].u;
        scr[rc(16 + pl, g)] = q[1][0].u; scr[rc(16 + pl, g + 4)] = q[1][1].u;
        capl(5, pl, q[0]); capl(5, 16 + pl, q[1]);
    }
    // lev6 (16 pairs)
    {
        int rL[1] = {2 * pl}, rR[1] = {2 * pl + 1};
        U4H8 q1[1][2];
        combine<1, false>(scr, rL, rR, wfd, pl, g, q1);
        scr[rc(pl, g)] = q1[0][0].u; scr[rc(pl, g + 4)] = q1[0][1].u;
        capl(6, pl, q1[0]);
    }
    // steps 1..10: walk lev `wl` on lanes pl 14/15; tree lev wl+6 on lanes pl<np (wl<=4)
    int cur_lo = 128, cur_hi = 130;  // SV(0,0), SV(0,2)
#pragma unroll 1
    for (int wl = 1; wl <= 10; ++wl) {
        int il = lo >> wl, ih = hi >> wl;
        int ilc = lo >> (wl - 1), ihc = hi >> (wl - 1);
        auto child_row = [&](int c) -> int {
            if (c == ilc) return cur_lo;
            if (c == ihc) return cur_hi;
            int clow = c << (wl - 1);
            int chigh = clow + (1 << (wl - 1)) - 1;
            if (lo <= clow && hi >= chigh)
                return 128 + (wl - 1) * 4 + ((c == (ilc ^ 1)) ? 1 : 3);
            return 172;  // inf
        };
        int np = (wl <= 4) ? (16 >> wl) : 0;
        int rowL, rowR, dst;
        bool wm, istree;
        if (pl < np)      { rowL = 2 * pl; rowR = 2 * pl + 1; dst = pl; wm = true; istree = true; }
        else if (pl == 14){ rowL = child_row(2 * il); rowR = child_row(2 * il + 1); dst = 173; wm = true; istree = false; }
        else if (pl == 15){ rowL = child_row(2 * ih); rowR = child_row(2 * ih + 1); dst = 174; wm = true; istree = false; }
        else              { rowL = 0; rowR = 1; dst = 175; wm = false; istree = false; }
        int rLa[1] = {rowL}, rRa[1] = {rowR};
        U4H8 q1[1][2];
        combine<1, true>(scr, rLa, rRa, wfd, pl, g, q1);
        if (wm) { scr[rc(dst, g)] = q1[0][0].u; scr[rc(dst, g + 4)] = q1[0][1].u; }
        if (istree) capl(wl + 6, pl, q1[0]);
        int low = il << wl, high = low + (1 << wl) - 1;
        cur_lo = (lo <= low && hi >= high) ? (128 + wl * 4) : 173;
        int low2 = ih << wl, high2 = low2 + (1 << wl) - 1;
        cur_hi = (lo <= low2 && hi >= high2) ? (128 + wl * 4 + 2) : 174;
    }
    // final linear
    float rv = (float)((_Float16*)scr)[rc(cur_lo, lane >> 3) * 8 + (lane & 7)];
#pragma unroll
    for (int c = 0; c < NCLS; ++c) {
        float s = wave_sum(rv * lin_w[c * 64 + lane]);
        if (lane == 0) out[b * NCLS + c] = s;
    }
}

extern "C" void kernel_launch(void* const* d_in, const int* in_sizes, int n_in,
                              void* d_out, int out_size, void* d_ws, size_t ws_size,
                              hipStream_t stream) {
    const int* x = (const int*)d_in[0];
    const int* qlo = (const int*)d_in[1];
    const int* qhi = (const int*)d_in[2];
    const float* emb = (const float*)d_in[3];
    const float* rule_w = (const float*)d_in[4];
    const float* lin_w = (const float*)d_in[5];
    float* out = (float*)d_out;
    uint4* ws4 = (uint4*)d_ws;  // needs (1024 + 1024*140*8) uint4 ~= 18 MB
    setup_kernel<<<8, 256, 0, stream>>>(emb, rule_w, ws4);
    fold_kernel<<<2048, 256, 0, stream>>>(x, qlo, qhi, ws4);
    topwalk_kernel<<<512, 128, 0, stream>>>(qlo, qhi, lin_w, out, ws4);
}

// Round 9
// 54.649 us; speedup vs baseline: 1.3584x; 1.0554x over previous
//
#include <hip/hip_runtime.h>

#define NCLS 10

typedef _Float16 half8 __attribute__((ext_vector_type(8)));
typedef _Float16 h2 __attribute__((ext_vector_type(2)));
typedef __fp16 fp16x2 __attribute__((ext_vector_type(2)));
typedef float f32x4 __attribute__((ext_vector_type(4)));
typedef unsigned int u32;

#define MFMA(A, B, C) __builtin_amdgcn_mfma_f32_16x16x32_f16(A, B, C, 0, 0, 0)

union U4H8 { uint4 u; half8 h; h2 p[4]; u32 w[4]; };
union U2H4 { uint2 u; h2 p[2]; };
union HCVT { fp16x2 f; h2 h; u32 w; };

// node rows = 8 uint4 chunks (64 f16); physical chunk = c ^ (row&7)
__device__ __forceinline__ int rc(int row, int c) { return (row << 3) | (c ^ (row & 7)); }
__device__ __forceinline__ h2 pk2(float a, float b) { HCVT u; u.f = __builtin_amdgcn_cvt_pkrtz(a, b); return u.h; }
__device__ __forceinline__ u32 packh2(float a, float b) { HCVT u; u.f = __builtin_amdgcn_cvt_pkrtz(a, b); return u.w; }
__device__ __forceinline__ float fdot2f(h2 a, h2 b, float c) { return __builtin_amdgcn_fdot2(a, b, c, false); }
__device__ __forceinline__ float wave_sum(float v) {
#pragma unroll
    for (int m = 1; m < 64; m <<= 1) v += __shfl_xor(v, m, 64);
    return v;
}
__device__ __forceinline__ float red4(float v) {
    v += __shfl_xor(v, 16, 64);
    v += __shfl_xor(v, 32, 64);
    return v;
}

// N-stream 16-pair combine. Wd = W1-W0 single matvec. EXACT: true norms.
template <int N, bool EXACT>
__device__ __forceinline__ void combine(const uint4* src, const int (&rowL)[N],
                                        const int (&rowR)[N], const half8 (&wfd)[2][4],
                                        int pl, int g, U4H8 (&q)[N][2]) {
    U4H8 La[N][2], Ra[N][2];
#pragma unroll
    for (int n = 0; n < N; ++n)
#pragma unroll
        for (int kb = 0; kb < 2; ++kb) {
            La[n][kb].u = src[rc(rowL[n], g + 4 * kb)];
            Ra[n][kb].u = src[rc(rowR[n], g + 4 * kb)];
        }
    const uint2* s2 = (const uint2*)src;
    U2H4 rv[N][4];
#pragma unroll
    for (int n = 0; n < N; ++n)
#pragma unroll
        for (int mb = 0; mb < 4; ++mb)
            rv[n][mb].u = s2[rc(rowR[n], 2 * mb + (g >> 1)) * 2 + (g & 1)];
    float sd[N], lr[N], ll[N], rr[N];
#pragma unroll
    for (int n = 0; n < N; ++n) { sd[n] = 0.f; lr[n] = 0.f; ll[n] = 0.f; rr[n] = 0.f; }
#pragma unroll
    for (int mb = 0; mb < 4; ++mb)
#pragma unroll
        for (int n = 0; n < N; ++n) {
            f32x4 t = {0.f, 0.f, 0.f, 0.f};
#pragma unroll
            for (int kb = 0; kb < 2; ++kb) t = MFMA(wfd[kb][mb], La[n][kb].h, t);
            sd[n] = fdot2f(pk2(t[0], t[1]), rv[n][mb].p[0],
                           fdot2f(pk2(t[2], t[3]), rv[n][mb].p[1], sd[n]));
        }
#pragma unroll
    for (int n = 0; n < N; ++n)
#pragma unroll
        for (int kb = 0; kb < 2; ++kb)
#pragma unroll
            for (int i = 0; i < 4; ++i) {
                h2 l2 = La[n][kb].p[i], r2 = Ra[n][kb].p[i];
                lr[n] = fdot2f(l2, r2, lr[n]);
                if (EXACT) { ll[n] = fdot2f(l2, l2, ll[n]); rr[n] = fdot2f(r2, r2, rr[n]); }
            }
#pragma unroll
    for (int n = 0; n < N; ++n) {
        sd[n] = red4(sd[n]); lr[n] = red4(lr[n]);
        if (EXACT) { ll[n] = red4(ll[n]); rr[n] = red4(rr[n]); }
    }
#pragma unroll
    for (int n = 0; n < N; ++n) {
        float u = __expf(sd[n]);
        float a0 = __builtin_amdgcn_rcpf(1.f + u), a1 = 1.f - a0;
        float ms = EXACT ? (a0 * a0 * ll[n] + 2.f * a0 * a1 * lr[n] + a1 * a1 * rr[n]) * (1.f / 64.f)
                         : a0 * a0 + a1 * a1 + a0 * a1 * lr[n] * (2.f / 64.f);
        float sc = __builtin_amdgcn_rcpf(__builtin_amdgcn_sqrtf(ms + 1e-6f) + 1e-6f);
        h2 c0 = pk2(a0 * sc, a0 * sc), c1 = pk2(a1 * sc, a1 * sc);
#pragma unroll
        for (int kb = 0; kb < 2; ++kb)
#pragma unroll
            for (int i = 0; i < 4; ++i)
                q[n][kb].p[i] = c0 * La[n][kb].p[i] + c1 * Ra[n][kb].p[i];
    }
}

// ws layout (uint4): [0..511] Wd frags; [512..607] ermsh rows 0-11 (10 classes RMS'd,
// row10 rms'd inf (unused), row 11 RAW inf), linear; batch b lev3 nodes at
// 1024 + (b*128 + r)*8, r=0..127.
__device__ __forceinline__ void load_wfd(const uint4* ws4, half8 (&wfd)[2][4], int lane) {
#pragma unroll
    for (int fm = 0; fm < 8; ++fm) {
        U4H8 t;
        t.u = ws4[fm * 64 + lane];
        wfd[fm >> 2][fm & 3] = t.h;
    }
}

// ======================= kernel 0: setup =======================
__global__ void setup_kernel(const float* __restrict__ emb,
                             const float* __restrict__ rule_w, uint4* __restrict__ ws4) {
    int tid = threadIdx.x;
    int idx = blockIdx.x * 256 + tid;  // 0..2047
    {
        int e2 = idx & 3, lane = (idx >> 2) & 63, fm = idx >> 8;
        int kb = fm >> 2, mb = fm & 3, pl = lane & 15, g = lane >> 4;
        int i0 = 32 * kb + 8 * g + 2 * e2, j = 16 * mb + pl;
        float d0 = rule_w[4096 + i0 * 64 + j] - rule_w[i0 * 64 + j];
        float d1 = rule_w[4096 + (i0 + 1) * 64 + j] - rule_w[(i0 + 1) * 64 + j];
        ((u32*)ws4)[idx] = packh2(d0, d1);
    }
    if (blockIdx.x == 0 && tid < 64) {
        int lane = tid;
        u32* eg = (u32*)(ws4 + 512);
        for (int r = 0; r < 11; ++r) {
            float e = emb[r * 64 + lane];
            float ms = wave_sum(e * e) * (1.f / 64.f);
            float v = e * __builtin_amdgcn_rcpf(__builtin_amdgcn_sqrtf(ms + 1e-6f) + 1e-6f);
            u32 w = packh2(v, __shfl_xor(v, 1, 64));
            if ((lane & 1) == 0) eg[r * 32 + (lane >> 1)] = w;
        }
        float e = emb[640 + lane];  // raw inf token -> row 11
        u32 w = packh2(e, __shfl_xor(e, 1, 64));
        if ((lane & 1) == 0) eg[11 * 32 + (lane >> 1)] = w;
    }
}

// ======================= kernel 1: fold lev1-3 (1 wave = 1 subtree) ==========
__global__ void __launch_bounds__(64, 4) fold_kernel(
    const int* __restrict__ x, uint4* __restrict__ ws4) {
    __shared__ uint4 trs[(64 + 12) * 8];  // 9.5 KB: rows 0-63 tree, 64-75 ermsh
    const int lane = threadIdx.x;
    const int pl = lane & 15, g = lane >> 4;
    const int b = blockIdx.x >> 3, s = blockIdx.x & 7;

    half8 wfd[2][4];
    load_wfd(ws4, wfd, lane);
    {
        int r = lane >> 3, c = lane & 7;
        trs[rc(64 + r, c)] = ws4[512 + lane];
        int idx = lane + 64;
        if (idx < 96) { r = idx >> 3; c = idx & 7; trs[rc(64 + r, c)] = ws4[512 + idx]; }
    }
    const int2* x2 = (const int2*)x;
    int2 c00 = x2[b * 512 + s * 64 + pl];
    int2 c01 = x2[b * 512 + s * 64 + 16 + pl];
    int2 c10 = x2[b * 512 + s * 64 + 32 + pl];
    int2 c11 = x2[b * 512 + s * 64 + 48 + pl];
    asm volatile("s_waitcnt lgkmcnt(0) vmcnt(0)" ::: "memory");

    U4H8 q[2][2];
    // lev1 pairs 0-31 -> rows 0-31
    {
        int rL[2] = {64 + c00.x, 64 + c01.x}, rR[2] = {64 + c00.y, 64 + c01.y};
        combine<2, false>(trs, rL, rR, wfd, pl, g, q);
        trs[rc(pl, g)] = q[0][0].u;      trs[rc(pl, g + 4)] = q[0][1].u;
        trs[rc(16 + pl, g)] = q[1][0].u; trs[rc(16 + pl, g + 4)] = q[1][1].u;
    }
    // lev1 pairs 32-63 -> rows 32-63
    {
        int rL[2] = {64 + c10.x, 64 + c11.x}, rR[2] = {64 + c10.y, 64 + c11.y};
        combine<2, false>(trs, rL, rR, wfd, pl, g, q);
        trs[rc(32 + pl, g)] = q[0][0].u; trs[rc(32 + pl, g + 4)] = q[0][1].u;
        trs[rc(48 + pl, g)] = q[1][0].u; trs[rc(48 + pl, g + 4)] = q[1][1].u;
    }
    asm volatile("s_waitcnt lgkmcnt(0)" ::: "memory");
    // lev2 (32 pairs) -> rows 0-31
    {
        int rL[2] = {2 * pl, 32 + 2 * pl}, rR[2] = {2 * pl + 1, 33 + 2 * pl};
        combine<2, false>(trs, rL, rR, wfd, pl, g, q);
        trs[rc(pl, g)] = q[0][0].u;      trs[rc(pl, g + 4)] = q[0][1].u;
        trs[rc(16 + pl, g)] = q[1][0].u; trs[rc(16 + pl, g + 4)] = q[1][1].u;
    }
    asm volatile("s_waitcnt lgkmcnt(0)" ::: "memory");
    // lev3 (16 pairs) -> global lev3 rows (linear chunks)
    {
        int rL[1] = {2 * pl}, rR[1] = {2 * pl + 1};
        U4H8 q1[1][2];
        combine<1, false>(trs, rL, rR, wfd, pl, g, q1);
        long gr = 1024 + (long)(b * 128 + s * 16 + pl) * 8;
        ws4[gr + g] = q1[0][0].u;
        ws4[gr + 4 + g] = q1[0][1].u;
    }
}

// ======================= kernel 2: top fold + sv rebuild + query walk ========
// scratch rows: 0-127 tree (lev3, folded in place), 128+l*4+s sv (l=0..10 ->
// 128-171), 173 res_lo, 174 res_hi, 175-182 A-call lev1 nodes, 184-195 ermsh
// (195 = raw inf)
__global__ void __launch_bounds__(64, 2) topwalk_kernel(
    const int* __restrict__ x, const int* __restrict__ qlo_p,
    const int* __restrict__ qhi_p, const float* __restrict__ lin_w,
    float* __restrict__ out, const uint4* __restrict__ ws4) {
    __shared__ uint4 scr[196 * 8];  // 24.5 KB
    const int lane = threadIdx.x;
    const int pl = lane & 15, g = lane >> 4;
    const int b = blockIdx.x;
    const int lo = qlo_p[b], hi = qhi_p[b];

    half8 wfd[2][4];
    load_wfd(ws4, wfd, lane);
    {
        int r = lane >> 3, c = lane & 7;
        scr[rc(184 + r, c)] = ws4[512 + lane];
        int idx = lane + 64;
        if (idx < 96) { r = idx >> 3; c = idx & 7; scr[rc(184 + r, c)] = ws4[512 + idx]; }
    }
#pragma unroll
    for (int i = 0; i < 16; ++i) {
        int idx = i * 64 + lane;
        int r = idx >> 3, c = idx & 7;
        scr[rc(r, c)] = ws4[1024 + (long)b * 1024 + idx];
    }
    asm volatile("s_waitcnt lgkmcnt(0) vmcnt(0)" ::: "memory");
    // sv lev3 (from tree rows, before lev4 overwrites) + sv lev0 (ermsh by class)
    if (lane < 32) {
        int slot = lane >> 3, c = lane & 7;
        int il3 = lo >> 3, ih3 = hi >> 3;
        int t3 = (slot == 0) ? il3 : (slot == 1) ? (il3 ^ 1) : (slot == 2) ? ih3 : (ih3 ^ 1);
        scr[rc(140 + slot, c)] = scr[rc(t3, c)];
        int t0 = (slot == 0) ? lo : (slot == 1) ? (lo ^ 1) : (slot == 2) ? hi : (hi ^ 1);
        int cls = x[b * 1024 + t0];
        scr[rc(128 + slot, c)] = scr[rc(184 + cls, c)];
    }
    asm volatile("s_waitcnt lgkmcnt(0) vmcnt(0)" ::: "memory");

    auto capl = [&](int lev, int node, const U4H8 (&qq)[2]) {
        int il = lo >> lev, ih = hi >> lev, cnt = 1024 >> lev;
        int svb = 128 + lev * 4;
        if (node == il) { scr[rc(svb, g)] = qq[0].u; scr[rc(svb, g + 4)] = qq[1].u; }
        if (((il ^ 1) < cnt) && node == (il ^ 1)) { scr[rc(svb + 1, g)] = qq[0].u; scr[rc(svb + 1, g + 4)] = qq[1].u; }
        if (node == ih) { scr[rc(svb + 2, g)] = qq[0].u; scr[rc(svb + 2, g + 4)] = qq[1].u; }
        if (((ih ^ 1) < cnt) && node == (ih ^ 1)) { scr[rc(svb + 3, g)] = qq[0].u; scr[rc(svb + 3, g + 4)] = qq[1].u; }
    };

    U4H8 q[2][2];
    // lev4 (64 pairs): 2 calls <2>
    {
        int rL[2] = {2 * pl, 32 + 2 * pl}, rR[2] = {2 * pl + 1, 33 + 2 * pl};
        combine<2, false>(scr, rL, rR, wfd, pl, g, q);
        scr[rc(pl, g)] = q[0][0].u;      scr[rc(pl, g + 4)] = q[0][1].u;
        scr[rc(16 + pl, g)] = q[1][0].u; scr[rc(16 + pl, g + 4)] = q[1][1].u;
        capl(4, pl, q[0]); capl(4, 16 + pl, q[1]);
    }
    {
        int rL[2] = {64 + 2 * pl, 96 + 2 * pl}, rR[2] = {65 + 2 * pl, 97 + 2 * pl};
        combine<2, false>(scr, rL, rR, wfd, pl, g, q);
        scr[rc(32 + pl, g)] = q[0][0].u; scr[rc(32 + pl, g + 4)] = q[0][1].u;
        scr[rc(48 + pl, g)] = q[1][0].u; scr[rc(48 + pl, g + 4)] = q[1][1].u;
        capl(4, 32 + pl, q[0]); capl(4, 48 + pl, q[1]);
    }
    asm volatile("s_waitcnt lgkmcnt(0)" ::: "memory");
    // lev5 (32 pairs)
    {
        int rL[2] = {2 * pl, 32 + 2 * pl}, rR[2] = {2 * pl + 1, 33 + 2 * pl};
        combine<2, false>(scr, rL, rR, wfd, pl, g, q);
        scr[rc(pl, g)] = q[0][0].u;      scr[rc(pl, g + 4)] = q[0][1].u;
        scr[rc(16 + pl, g)] = q[1][0].u; scr[rc(16 + pl, g + 4)] = q[1][1].u;
        capl(5, pl, q[0]); capl(5, 16 + pl, q[1]);
    }
    asm volatile("s_waitcnt lgkmcnt(0)" ::: "memory");
    // lev6 (16 pairs) + A-ride: 8 lev1 sv-support nodes from leaves
    const int il1 = lo >> 1, ih1 = hi >> 1, il2 = lo >> 2, ih2 = hi >> 2;
    {
        const int2* x2 = (const int2*)x;
        bool aact = pl < 8;
        int n1 = 0;
        if (aact) {
            int base2 = (pl < 4) ? ((pl < 2) ? il2 : (il2 ^ 1))
                                 : ((pl < 6) ? ih2 : (ih2 ^ 1));
            n1 = 2 * base2 + (pl & 1);
        }
        int2 lv = aact ? x2[b * 512 + n1] : make_int2(0, 0);
        int rL[2] = {2 * pl, aact ? 184 + lv.x : 184};
        int rR[2] = {2 * pl + 1, aact ? 184 + lv.y : 184};
        combine<2, false>(scr, rL, rR, wfd, pl, g, q);
        scr[rc(pl, g)] = q[0][0].u; scr[rc(pl, g + 4)] = q[0][1].u;
        capl(6, pl, q[0]);
        if (aact) { scr[rc(175 + pl, g)] = q[1][0].u; scr[rc(175 + pl, g + 4)] = q[1][1].u; }
    }
    asm volatile("s_waitcnt lgkmcnt(0)" ::: "memory");
    // sv lev1 copies from A rows
    if (lane < 32) {
        int slot = lane >> 3, c = lane & 7;
        int srcrow = (slot == 0) ? 175 + (il1 & 1)
                   : (slot == 1) ? 175 + ((il1 & 1) ^ 1)
                   : (slot == 2) ? 179 + (ih1 & 1)
                                 : 179 + ((ih1 & 1) ^ 1);
        scr[rc(132 + slot, c)] = scr[rc(srcrow, c)];
    }
    asm volatile("s_waitcnt lgkmcnt(0)" ::: "memory");

    // walk steps wl=1..10; tree lev wl+6 rides on pl<np (wl<=4); B (sv lev2) rides wl=1
    int cur_lo = 128, cur_hi = 130;
#pragma unroll 1
    for (int wl = 1; wl <= 10; ++wl) {
        int il = lo >> wl, ih = hi >> wl;
        int ilc = lo >> (wl - 1), ihc = hi >> (wl - 1);
        auto child_row = [&](int c) -> int {
            if (c == ilc) return cur_lo;
            if (c == ihc) return cur_hi;
            int clow = c << (wl - 1);
            int chigh = clow + (1 << (wl - 1)) - 1;
            if (lo <= clow && hi >= chigh)
                return 128 + (wl - 1) * 4 + ((c == (ilc ^ 1)) ? 1 : 3);
            return 195;  // raw inf
        };
        int np = (wl <= 4) ? (16 >> wl) : 0;
        int rowL, rowR, dst;
        bool wm = true, istree = false;
        if (pl < np)       { rowL = 2 * pl; rowR = 2 * pl + 1; dst = pl; istree = true; }
        else if (wl == 1 && pl >= 8 && pl < 12) {
            int s2 = pl - 8; rowL = 175 + 2 * s2; rowR = 176 + 2 * s2; dst = 136 + s2;
        }
        else if (pl == 14) { rowL = child_row(2 * il); rowR = child_row(2 * il + 1); dst = 173; }
        else if (pl == 15) { rowL = child_row(2 * ih); rowR = child_row(2 * ih + 1); dst = 174; }
        else               { rowL = 195; rowR = 195; dst = 175; wm = false; }
        int rLa[1] = {rowL}, rRa[1] = {rowR};
        U4H8 q1[1][2];
        combine<1, true>(scr, rLa, rRa, wfd, pl, g, q1);
        if (wm) { scr[rc(dst, g)] = q1[0][0].u; scr[rc(dst, g + 4)] = q1[0][1].u; }
        if (istree) capl(wl + 6, pl, q1[0]);
        int low = il << wl, high = low + (1 << wl) - 1;
        cur_lo = (lo <= low && hi >= high) ? (128 + wl * 4) : 173;
        int low2 = ih << wl, high2 = low2 + (1 << wl) - 1;
        cur_hi = (lo <= low2 && hi >= high2) ? (128 + wl * 4 + 2) : 174;
        asm volatile("s_waitcnt lgkmcnt(0)" ::: "memory");
    }
    // final linear
    float rv = (float)((_Float16*)scr)[rc(cur_lo, lane >> 3) * 8 + (lane & 7)];
#pragma unroll
    for (int c = 0; c < NCLS; ++c) {
        float s = wave_sum(rv * lin_w[c * 64 + lane]);
        if (lane == 0) out[b * NCLS + c] = s;
    }
}

extern "C" void kernel_launch(void* const* d_in, const int* in_sizes, int n_in,
                              void* d_out, int out_size, void* d_ws, size_t ws_size,
                              hipStream_t stream) {
    const int* x = (const int*)d_in[0];
    const int* qlo = (const int*)d_in[1];
    const int* qhi = (const int*)d_in[2];
    const float* emb = (const float*)d_in[3];
    const float* rule_w = (const float*)d_in[4];
    const float* lin_w = (const float*)d_in[5];
    float* out = (float*)d_out;
    uint4* ws4 = (uint4*)d_ws;  // 1024 + 1024*128*8 uint4 ~= 16.8 MB
    setup_kernel<<<8, 256, 0, stream>>>(emb, rule_w, ws4);
    fold_kernel<<<8192, 64, 0, stream>>>(x, ws4);
    topwalk_kernel<<<1024, 64, 0, stream>>>(x, qlo, qhi, lin_w, out, ws4);
}